// Round 5
// baseline (64.961 us; speedup 1.0000x reference)
//
#include <hip/hip_runtime.h>

#define EPS 1e-5f
#define ONE_M_EPS (1.0f - 1e-5f)
#define NROW 2048
#define FF 20
#define DH 64
#define PADW (DH + 4)        // 68: rows stay 16B-aligned, banks spread
#define NPAIR (FF * FF)      // 400
#define NPAIR2 (NPAIR + FF)  // + f.Q dots

__device__ __forceinline__ float frcp(float x) { return __builtin_amdgcn_rcpf(x); }
__device__ __forceinline__ float fsq(float x) { return __builtin_amdgcn_sqrtf(x); }

__device__ __forceinline__ float wred(float v) {
#pragma unroll
  for (int m = 32; m >= 1; m >>= 1) v += __shfl_xor(v, m, 64);
  return v;
}

__device__ __forceinline__ float ftanh(float x) {
  float ax = fabsf(x);
  float e = __expf(-2.f * ax);
  float t = (1.f - e) * frcp(1.f + e);
  return copysignf(t, x);
}

__device__ __forceinline__ float fatanh(float x) {  // x in [0, 1-EPS]
  return 0.5f * __logf((1.f + x) * frcp(1.f - x));
}

__device__ __forceinline__ float clampn(float x) {
  return fminf(fmaxf(x, EPS), ONE_M_EPS);
}

// exp(-acosh(arg)) without exp/log: 1/(arg + sqrt(arg^2-1))
__device__ __forceinline__ float expnacosh(float arg) {
  return frcp(arg + fsq(fmaxf(arg * arg - 1.f, 0.f)));
}

struct FeatParams {
  const float *emb0, *emb1, *win, *bin;
  float* fout;
};

struct ModeParams {
  const float* f;
  const int *Didx, *Qidx;
  const float *q1p, *qp, *qqp, *aw1, *ab1, *aw2, *wout, *bout;
  float* out;
};

// f = exp0(concat(emb0[x0], emb1[x1]) @ win + bin); both modes in one grid
__global__ __launch_bounds__(64) void feat_kernel(const int* __restrict__ x,
                                                  FeatParams ps, FeatParams pc) {
  const int bid = blockIdx.x;
  const int mode = bid >= NROW;
  const FeatParams P = mode ? pc : ps;
  const int n = bid - mode * NROW;
  const int l = threadIdx.x;
  __shared__ float u[DH];
  int x0 = x[n * 2 + 0];
  int x1 = x[n * 2 + 1];
  u[l] = (l < 32) ? P.emb0[x0 * 32 + l] : P.emb1[x1 * 32 + (l - 32)];
  __syncthreads();
  float acc = P.bin[l];
#pragma unroll
  for (int k = 0; k < DH; ++k) acc = fmaf(u[k], P.win[k * DH + l], acc);
  float a2 = wred(acc * acc);
  float nn = fsq(a2 + 1e-15f);
  P.fout[n * DH + l] = ftanh(nn) * frcp(fmaxf(nn, EPS)) * acc;
}

__global__ __launch_bounds__(256) void mode_kernel(ModeParams pm0, ModeParams pm1) {
  const int bid = blockIdx.x;
  const int mode = bid >= NROW;
  const ModeParams P = mode ? pm1 : pm0;
  const int n = bid - mode * NROW;
  const int tid = threadIdx.x;
  const int l = tid & 63;
  const int w = tid >> 6;

  __shared__ alignas(16) float Ds[FF][PADW];  // D rows; becomes h_neigh after P5
  __shared__ alignas(16) float Qs[FF][PADW];  // raw Q rows (distances)
  __shared__ alignas(16) float fs_[PADW];
  __shared__ alignas(16) float Gm[NPAIR];  // raw softmax numerators exp(-d)
  __shared__ float Fq[FF];                 // f.Q dots
  __shared__ float D2[FF], DN[FF], DA[FF];  // DA -> WH = atanh(|h|)/|h| after P5
  __shared__ float Q2[FF], WQ[FF];          // WQ = atanh(|Q|)/|Q|
  __shared__ float zb[2][DH];
  __shared__ float ub[DH];
  __shared__ float pb[4][DH];

  const float* f = P.f;
  float fv = f[n * DH + l];

  // ---- P0: gather tiles ----
  for (int i = w; i < FF; i += 4) {
    Ds[i][l] = f[P.Didx[n * FF + i] * DH + l];
    Qs[i][l] = f[P.Qidx[n * FF + i] * DH + l];
  }
  if (w == 0) fs_[l] = fv;
  float f2 = wred(fv * fv);  // per-wave uniform
  float fnc = clampn(fsq(f2 + 1e-15f));
  float fA = fatanh(fnc);
  float q1 = P.q1p[0], qsc = P.qp[0], qqsc = P.qqp[0];
  __syncthreads();

  // ---- P1: row norms as per-thread self-dots (wave0: D, wave1: Q) ----
  if (w < 2 && l < FF) {
    const float4* rp =
        (w == 0) ? (const float4*)(&Ds[l][0]) : (const float4*)(&Qs[l][0]);
    float dot = 0.f;
#pragma unroll
    for (int kk = 0; kk < DH / 4; ++kk) {
      float4 a = rp[kk];
      dot = fmaf(a.x, a.x, dot);
      dot = fmaf(a.y, a.y, dot);
      dot = fmaf(a.z, a.z, dot);
      dot = fmaf(a.w, a.w, dot);
    }
    float nc = clampn(fsq(dot + 1e-15f));
    float at = fatanh(nc);
    if (w == 0) {
      D2[l] = dot; DN[l] = nc; DA[l] = at;
    } else {
      Q2[l] = dot; WQ[l] = at * frcp(nc);
    }
  }
  __syncthreads();

  // scaled Q columns in registers: qregS[j] = (atanh(|Q_j|)/|Q_j|) * Q_j[l]
  float qregS[FF];
#pragma unroll
  for (int j = 0; j < FF; ++j) qregS[j] = WQ[j] * Qs[j][l];

  // ---- P2: per-thread pair dots -> softmax numerators ----
  for (int p = tid; p < NPAIR2; p += 256) {
    int i = p / FF;
    int j = p - i * FF;
    const float4* ap =
        (i < FF) ? (const float4*)(&Ds[i][0]) : (const float4*)(&fs_[0]);
    const float4* bp = (const float4*)(&Qs[j][0]);
    float dot = 0.f;
#pragma unroll
    for (int kk = 0; kk < DH / 4; ++kk) {
      float4 a = ap[kk];
      float4 b = bp[kk];
      dot = fmaf(a.x, b.x, dot);
      dot = fmaf(a.y, b.y, dot);
      dot = fmaf(a.z, b.z, dot);
      dot = fmaf(a.w, b.w, dot);
    }
    if (i < FF) {
      float d2 = D2[i] + Q2[j] - 2.f * dot;
      float den = fmaxf((1.f - D2[i]) * (1.f - Q2[j]), EPS);
      float arg = fmaxf(1.f + 2.f * d2 * frcp(den), 1.f + 1e-7f);
      Gm[p] = expnacosh(arg);
    } else {
      Fq[j] = dot;
    }
  }
  __syncthreads();

  // ---- P5: per-slot weighted sum (softmax + log0/mob_scalar collapsed) ----
  for (int i = w; i < FF; i += 4) {
    float ssum = 0.f, accR = 0.f;
    const float4* gr = (const float4*)(&Gm[i * FF]);
#pragma unroll
    for (int jq = 0; jq < FF / 4; ++jq) {
      float4 g4 = gr[jq];
      ssum += ((g4.x + g4.y) + (g4.z + g4.w));
      accR = fmaf(g4.x, qregS[4 * jq + 0], accR);
      accR = fmaf(g4.y, qregS[4 * jq + 1], accR);
      accR = fmaf(g4.z, qregS[4 * jq + 2], accR);
      accR = fmaf(g4.w, qregS[4 * jq + 3], accR);
    }
    float acc = accR * frcp(ssum);
    float a2 = wred(acc * acc);
    float nn = fsq(a2 + 1e-15f);
    float ec = ftanh(nn) * frcp(fmaxf(nn, EPS));
    float nh = ec * acc;
    float fDc = ftanh(q1 * DA[i]) * frcp(DN[i]);
    float dl = Ds[i][l];
    float xv = fDc * dl;
    float x2 = fDc * fDc * D2[i];
    float y2 = ec * ec * a2;
    float xy = wred(xv * nh);
    float al = 1.f + 2.f * xy + y2;
    float be = 1.f - x2;
    float rd = frcp(fmaxf(1.f + 2.f * xy + x2 * y2, EPS));
    Ds[i][l] = (al * xv + be * nh) * rd;
    float h2 = (al * al * x2 + 2.f * al * be * xy + be * be * y2) * rd * rd;
    if (l == 0) {
      float nc = clampn(fsq(h2 + 1e-15f));
      D2[i] = h2;
      DA[i] = fatanh(nc) * frcp(nc);  // WH for aggregate collapse
    }
  }
  __syncthreads();

  // ---- P6: aggregates, fully wave-local (wave0: e1 over H; wave1: e2 over Q)
  if (w < 2) {
    float a1 = 0.f;
    if (w == 0) {
      if (l < FF) {
        const float4* ap = (const float4*)(&fs_[0]);
        const float4* bp = (const float4*)(&Ds[l][0]);
        float dot = 0.f;
#pragma unroll
        for (int kk = 0; kk < DH / 4; ++kk) {
          float4 a = ap[kk];
          float4 b = bp[kk];
          dot = fmaf(a.x, b.x, dot);
          dot = fmaf(a.y, b.y, dot);
          dot = fmaf(a.z, b.z, dot);
          dot = fmaf(a.w, b.w, dot);
        }
        float d2 = f2 + D2[l] - 2.f * dot;
        float den = fmaxf((1.f - f2) * (1.f - D2[l]), EPS);
        float arg = fmaxf(1.f + 2.f * d2 * frcp(den), 1.f + 1e-7f);
        a1 = expnacosh(arg);
      }
    } else {
      if (l < FF) {
        float d2 = f2 + Q2[l] - 2.f * Fq[l];
        float den = fmaxf((1.f - f2) * (1.f - Q2[l]), EPS);
        float arg = fmaxf(1.f + 2.f * d2 * frcp(den), 1.f + 1e-7f);
        a1 = expnacosh(arg);
      }
    }
    float s = wred(a1);
    // coeff_j = att_j * W_j (W for H folded from DA; W for Q folded in qregS)
    float c = 0.f;
    if (l < FF) c = a1 * frcp(s) * ((w == 0) ? DA[l] : 1.f);
    float accE = 0.f;
    if (w == 0) {
#pragma unroll
      for (int j = 0; j < FF; ++j)
        accE = fmaf(__shfl(c, j, 64), Ds[j][l], accE);
    } else {
#pragma unroll
      for (int j = 0; j < FF; ++j)
        accE = fmaf(__shfl(c, j, 64), qregS[j], accE);
    }
    float a2 = wred(accE * accE);
    float nn = fsq(a2 + 1e-15f);
    float ec = ftanh(nn) * frcp(fmaxf(nn, EPS));
    float nTE = ec * accE;
    float r = (w == 0) ? qsc : qqsc;
    float fsc = ftanh(r * fA) * frcp(fnc);
    float xv = fsc * fv;
    float x2 = fsc * fsc * f2;
    float y2 = ec * ec * a2;
    float xy = wred(xv * nTE);
    float al = 1.f + 2.f * xy + y2;
    float be = 1.f - x2;
    float rd = frcp(fmaxf(1.f + 2.f * xy + x2 * y2, EPS));
    float ev = (al * xv + be * nTE) * rd;
    float es = (al * al * x2 + 2.f * al * be * xy + be * be * y2) * rd * rd;
    float n1 = clampn(fsq(es + 1e-15f));
    zb[w][l] = fatanh(n1) * frcp(n1) * ev;
  }
  __syncthreads();

  // ---- P7: beta softmax + rst + u (wave0) ----
  if (w == 0) {
    int p_ = l >> 5, c_ = l & 31;
    float mm = P.ab1[c_];
#pragma unroll
    for (int k = 0; k < DH; ++k) mm = fmaf(zb[p_][k], P.aw1[k * 32 + c_], mm);
    float tt = ftanh(mm);
    float sr = tt * P.aw2[c_];
#pragma unroll
    for (int m = 16; m >= 1; m >>= 1) sr += __shfl_xor(sr, m, 64);
    float s0 = __shfl(sr, 0, 64);
    float s1 = __shfl(sr, 32, 64);
    float bm = fmaxf(s0, s1);
    float b0 = __expf(s0 - bm), b1 = __expf(s1 - bm);
    float bi = frcp(b0 + b1);
    b0 *= bi;
    b1 *= bi;
    float rv = fmaf(b0, zb[0][l], b1 * zb[1][l]);
    float r2 = wred(rv * rv);
    float rn = fsq(r2 + 1e-15f);
    float sc = ftanh(rn) * frcp(fmaxf(rn, EPS));
    float rst = sc * rv;
    float rr = sc * sc * r2;
    float rc = clampn(fsq(rr + 1e-15f));
    ub[l] = fatanh(rc) * frcp(rc) * rst;
  }
  __syncthreads();

  // ---- P8: out = exp0(u @ wout + bout), k-split over 4 waves ----
  {
    float oo = 0.f;
#pragma unroll
    for (int k = 0; k < DH / 4; ++k) {
      int kk = w * (DH / 4) + k;
      oo = fmaf(ub[kk], P.wout[kk * DH + l], oo);
    }
    pb[w][l] = oo;
  }
  __syncthreads();
  if (w == 0) {
    float oo = P.bout[l] + ((pb[0][l] + pb[1][l]) + (pb[2][l] + pb[3][l]));
    float o2 = wred(oo * oo);
    float on = fsq(o2 + 1e-15f);
    P.out[n * DH + l] = ftanh(on) * frcp(fmaxf(on, EPS)) * oo;
  }
}

extern "C" void kernel_launch(void* const* d_in, const int* in_sizes, int n_in,
                              void* d_out, int out_size, void* d_ws,
                              size_t ws_size, hipStream_t stream) {
  const int* x = (const int*)d_in[0];
  const int* idx_sim = (const int*)d_in[1];
  const int* idx_cor = (const int*)d_in[2];
  const float* p[2][12];
  for (int m = 0; m < 2; ++m)
    for (int k = 0; k < 12; ++k) p[m][k] = (const float*)d_in[3 + m * 12 + k];

  float* fsim = (float*)d_ws;
  float* fcor = fsim + NROW * DH;
  float* out = (float*)d_out;

  FeatParams fps = {p[0][0], p[0][1], p[0][2], p[0][3], fsim};
  FeatParams fpc = {p[1][0], p[1][1], p[1][2], p[1][3], fcor};
  feat_kernel<<<2 * NROW, 64, 0, stream>>>(x, fps, fpc);

  // mode 'sim': D = f[idx_cor], Q = f[idx_sim]; mode 'cor': swapped
  ModeParams m0 = {fsim, idx_cor, idx_sim, p[0][6], p[0][4], p[0][5],
                   p[0][7], p[0][8], p[0][9], p[0][10], p[0][11], out};
  ModeParams m1 = {fcor, idx_sim, idx_cor, p[1][6], p[1][4], p[1][5],
                   p[1][7], p[1][8], p[1][9], p[1][10], p[1][11], out + NROW * DH};
  mode_kernel<<<2 * NROW, 256, 0, stream>>>(m0, m1);
}